// Round 9
// baseline (429.191 us; speedup 1.0000x reference)
//
#include <hip/hip_runtime.h>

// Seq2seq LSTM, round 9: EXACT round-5 structure (verified PASS, 262 us),
// with halved per-block rows: BR=4, 1024 blocks -> 4 blocks/CU so the
// serialized phases (MFMA -> G store -> barrier -> trans cell-update) of
// independent blocks overlap. prep kernel + ws layout byte-identical to r5.
//   i,f,o gates scaled by -log2e -> sigmoid = rcp(1 + exp2(g))
//   g gate scaled by +2*log2e   -> tanh    = 1 - 2*rcp(1 + exp2(g))

#define NTHREADS 512
#define NBLOCKS  1024
#define BR       4

typedef __attribute__((ext_vector_type(8))) short short8;
typedef __attribute__((ext_vector_type(4))) float f32x4;

#define FRAG_ELEMS 51200
#define BIAS_BYTE_OFF 204800
#define L2E 1.4426950408889634f

__device__ __forceinline__ unsigned short f2bf(float f) {
    unsigned int u = __float_as_uint(f);
    return (unsigned short)((u + 0x7fff + ((u >> 16) & 1)) >> 16);   // RNE
}
__device__ __forceinline__ float bf2f(unsigned short s) {
    return __uint_as_float(((unsigned int)s) << 16);
}
__device__ __forceinline__ float ex2(float x) {
    float r; asm("v_exp_f32 %0, %1" : "=v"(r) : "v"(x)); return r;
}
__device__ __forceinline__ float rcpf_(float x) { return __builtin_amdgcn_rcpf(x); }

// h = cell(g, c) with pre-scaled gates
__device__ __forceinline__ float cellup(const f32x4 g, float& c) {
    float si = rcpf_(1.f + ex2(g[0]));
    float sf = rcpf_(1.f + ex2(g[1]));
    float tg = fmaf(-2.f, rcpf_(1.f + ex2(g[2])), 1.f);
    float so = rcpf_(1.f + ex2(g[3]));
    c = fmaf(sf, c, si * tg);
    float tc = fmaf(-2.f, rcpf_(1.f + ex2(c * (2.f * L2E))), 1.f);
    return so * tc;
}

// frag[((t*4+s)*64 + lane)*8 + e] = scale(gate) * WT'[k][n], bf16
// k = s*32+(lane>>4)*8+e, n = t*16+(lane&15), n = 4*jcol + gate  (r5-identical)
__global__ void prep_kernel(const float* __restrict__ Wih_e, const float* __restrict__ Whh_e,
                            const float* __restrict__ bih_e, const float* __restrict__ bhh_e,
                            const float* __restrict__ Wih_d, const float* __restrict__ Whh_d,
                            const float* __restrict__ bih_d, const float* __restrict__ bhh_d,
                            void* __restrict__ ws)
{
    unsigned short* frag = (unsigned short*)ws;
    float* bias = (float*)((char*)ws + BIAS_BYTE_OFF);
    int gid = blockIdx.x * blockDim.x + threadIdx.x;
    int gsz = gridDim.x * blockDim.x;
    for (int i = gid; i < 2 * FRAG_ELEMS; i += gsz) {
        int which = i / FRAG_ELEMS;
        int e = i - which * FRAG_ELEMS;
        int j8 = e & 7, lane = (e >> 3) & 63, s = (e >> 9) & 3, t = e >> 11;
        int k = s * 32 + (lane >> 4) * 8 + j8;
        int n = t * 16 + (lane & 15);
        int jcol = n >> 2, gate = n & 3, col = gate * 100 + jcol;
        float scale = (gate == 2) ? (2.f * L2E) : -L2E;
        const float* Whh = which ? Whh_d : Whh_e;
        const float* Wih = which ? Wih_d : Wih_e;
        float v = 0.f;
        if (k < 100)      v = Whh[col * 100 + k];
        else if (k < 104) v = Wih[col * 4 + (k - 100)];
        frag[i] = f2bf(v * scale);
    }
    for (int i = gid; i < 800; i += gsz) {
        int which = i / 400, n = i - which * 400;
        int jcol = n >> 2, gate = n & 3, col = gate * 100 + jcol;
        float scale = (gate == 2) ? (2.f * L2E) : -L2E;
        bias[i] = scale * (which ? (bih_d[col] + bhh_d[col]) : (bih_e[col] + bhh_e[col]));
    }
}

__global__ __launch_bounds__(NTHREADS)
__attribute__((amdgpu_waves_per_eu(4)))
void seq2seq_kernel(
    const float* __restrict__ inputs,   // [200][4096][4]
    const void* __restrict__ ws,
    const float* __restrict__ Wy,       // [4][100]
    const float* __restrict__ by_g,     // [4]
    float* __restrict__ out)            // [30][4096][4]
{
    // A fragment order: elem = ((k>>3)*16 + row)*8 + (k&7); rows 4..15 stay 0
    __shared__ unsigned short A_frag[2048];      // 4 KB
    __shared__ float G_lds[4 * 404];             // 6.5 KB (rows 0..3 only)
    __shared__ float Wy_lds[404];                // Wy + by

    const unsigned short* fragE = (const unsigned short*)ws;
    const unsigned short* fragD = fragE + FRAG_ELEMS;
    const float* biasE = (const float*)((const char*)ws + BIAS_BYTE_OFF);
    const float* biasD = biasE + 400;

    const int tid = threadIdx.x;
    const int wid = tid >> 6;          // wave 0..7
    const int wl  = tid & 63;
    const int m   = wl & 15;           // A row / C col
    const int q   = wl >> 4;
    const int blk = blockIdx.x;

    for (int i = tid; i < 2048; i += NTHREADS) A_frag[i] = 0;

    // cell-update mapping: threads 0..399 own cell (row cr, col cj)
    const int cr = tid & 3, cj = tid >> 2;
    const bool isc = (tid < 400);
    float cst = 0.f;

    // x writers: tid 480..495 -> (row 0..3, comp 0..3)
    const bool isx = (tid >= 480) && (tid < 496);
    const int xu = tid - 480, xr = (xu >> 2) & 3, xc = xu & 3;
    const float* xsrc = inputs + ((size_t)blk * BR + xr) * 4 + xc;
    const int xelem = (192 + xr) * 8 + 4 + xc;   // k = 100+xc, row xr

    // weights: 3 tiles per wave (t = wid+8i, i<3) + tile 24 on wave 7  (r5-identical)
    short8 bfr[3][4]; float breg[3];
    short8 bfr24[4];  float breg24 = 0.f;
    #pragma unroll
    for (int i = 0; i < 3; ++i) {
        int t = wid + 8 * i;
        #pragma unroll
        for (int s = 0; s < 4; ++s)
            bfr[i][s] = *(const short8*)&fragE[((t * 4 + s) * 64 + wl) * 8];
        breg[i] = biasE[t * 16 + m];
    }
    if (wid == 7) {
        #pragma unroll
        for (int s = 0; s < 4; ++s)
            bfr24[s] = *(const short8*)&fragE[((24 * 4 + s) * 64 + wl) * 8];
        breg24 = biasE[24 * 16 + m];
    }

    float xreg = isx ? xsrc[0] : 0.f;            // x_0
    __syncthreads();                             // A zero-init done
    if (isx) {
        A_frag[xelem] = f2bf(xreg);
        xreg = xsrc[16384];                      // x_1
    }

    // ---------------- encoder: 200 steps ----------------
    for (int step = 0; step < 200; ++step) {
        __syncthreads();                         // B1: A (h,x) ready
        short8 af[4];
        #pragma unroll
        for (int s = 0; s < 4; ++s)
            af[s] = *(const short8*)&A_frag[(s * 64 + wl) * 8];
        #pragma unroll
        for (int i = 0; i < 3; ++i) {
            int t = wid + 8 * i;
            f32x4 acc = {breg[i], breg[i], breg[i], breg[i]};
            #pragma unroll
            for (int s = 0; s < 4; ++s)
                acc = __builtin_amdgcn_mfma_f32_16x16x32_bf16(af[s], bfr[i][s], acc, 0, 0, 0);
            if (q == 0) {                        // C rows 0..3 only
                #pragma unroll
                for (int r = 0; r < 4; ++r)
                    G_lds[r * 404 + t * 16 + m] = acc[r];
            }
        }
        if (wid == 7) {
            f32x4 acc = {breg24, breg24, breg24, breg24};
            #pragma unroll
            for (int s = 0; s < 4; ++s)
                acc = __builtin_amdgcn_mfma_f32_16x16x32_bf16(af[s], bfr24[s], acc, 0, 0, 0);
            if (q == 0) {
                #pragma unroll
                for (int r = 0; r < 4; ++r)
                    G_lds[r * 404 + 24 * 16 + m] = acc[r];
            }
        }
        __syncthreads();                         // B2: G ready, af reads done
        if (isc) {
            f32x4 g = *(const f32x4*)&G_lds[cr * 404 + 4 * cj];
            float h = cellup(g, cst);
            A_frag[((cj >> 3) * 16 + cr) * 8 + (cj & 7)] = f2bf(h);
        }
        if (isx && step < 199) {
            A_frag[xelem] = f2bf(xreg);
            if (step < 198) xreg = xsrc[(size_t)(step + 2) * 16384];
        }
    }

    // ---------------- switch to decoder ----------------
    #pragma unroll
    for (int i = 0; i < 3; ++i) {
        int t = wid + 8 * i;
        #pragma unroll
        for (int s = 0; s < 4; ++s)
            bfr[i][s] = *(const short8*)&fragD[((t * 4 + s) * 64 + wl) * 8];
        breg[i] = biasD[t * 16 + m];
    }
    if (wid == 7) {
        #pragma unroll
        for (int s = 0; s < 4; ++s)
            bfr24[s] = *(const short8*)&fragD[((24 * 4 + s) * 64 + wl) * 8];
        breg24 = biasD[24 * 16 + m];
    }
    cst = 0.f;                                   // c resets; h carries over
    if (isx) A_frag[xelem] = 0;                  // y_prev = 0
    for (int i = tid; i < 404; i += NTHREADS)
        Wy_lds[i] = (i < 400) ? Wy[i] : by_g[i - 400];

    const int yrow = tid >> 5, yln = tid & 31;
    const bool isy = (tid < 128);                // rows 0..3

    // ---------------- decoder: 30 autoregressive steps ----------------
    for (int step = 0; step < 30; ++step) {
        __syncthreads();                         // B1: A ready (+ Wy staged)
        short8 af[4];
        #pragma unroll
        for (int s = 0; s < 4; ++s)
            af[s] = *(const short8*)&A_frag[(s * 64 + wl) * 8];
        #pragma unroll
        for (int i = 0; i < 3; ++i) {
            int t = wid + 8 * i;
            f32x4 acc = {breg[i], breg[i], breg[i], breg[i]};
            #pragma unroll
            for (int s = 0; s < 4; ++s)
                acc = __builtin_amdgcn_mfma_f32_16x16x32_bf16(af[s], bfr[i][s], acc, 0, 0, 0);
            if (q == 0) {
                #pragma unroll
                for (int r = 0; r < 4; ++r)
                    G_lds[r * 404 + t * 16 + m] = acc[r];
            }
        }
        if (wid == 7) {
            f32x4 acc = {breg24, breg24, breg24, breg24};
            #pragma unroll
            for (int s = 0; s < 4; ++s)
                acc = __builtin_amdgcn_mfma_f32_16x16x32_bf16(af[s], bfr24[s], acc, 0, 0, 0);
            if (q == 0) {
                #pragma unroll
                for (int r = 0; r < 4; ++r)
                    G_lds[r * 404 + 24 * 16 + m] = acc[r];
            }
        }
        __syncthreads();                         // B2: G ready
        if (isc) {
            f32x4 g = *(const f32x4*)&G_lds[cr * 404 + 4 * cj];
            float h = cellup(g, cst);
            A_frag[((cj >> 3) * 16 + cr) * 8 + (cj & 7)] = f2bf(h);
        }
        __syncthreads();                         // B3: h complete
        if (isy) {
            float p0 = 0.f, p1 = 0.f, p2 = 0.f, p3 = 0.f;
            #pragma unroll
            for (int i = 0; i < 4; ++i) {
                int jj = yln + 32 * i;
                if (jj < 100) {
                    float hv = bf2f(A_frag[((jj >> 3) * 16 + yrow) * 8 + (jj & 7)]);
                    p0 = fmaf(Wy_lds[0 * 100 + jj], hv, p0);
                    p1 = fmaf(Wy_lds[1 * 100 + jj], hv, p1);
                    p2 = fmaf(Wy_lds[2 * 100 + jj], hv, p2);
                    p3 = fmaf(Wy_lds[3 * 100 + jj], hv, p3);
                }
            }
            #pragma unroll
            for (int mm = 16; mm >= 1; mm >>= 1) {
                p0 += __shfl_xor(p0, mm, 32);
                p1 += __shfl_xor(p1, mm, 32);
                p2 += __shfl_xor(p2, mm, 32);
                p3 += __shfl_xor(p3, mm, 32);
            }
            if (yln == 0) {
                float y0 = p0 + Wy_lds[400], y1 = p1 + Wy_lds[401];
                float y2 = p2 + Wy_lds[402], y3 = p3 + Wy_lds[403];
                *(float4*)&out[((size_t)step * 4096 + blk * BR + yrow) * 4] =
                    make_float4(y0, y1, y2, y3);
                A_frag[(192 + yrow) * 8 + 4] = f2bf(y0);   // y feedback
                A_frag[(192 + yrow) * 8 + 5] = f2bf(y1);
                A_frag[(192 + yrow) * 8 + 6] = f2bf(y2);
                A_frag[(192 + yrow) * 8 + 7] = f2bf(y3);
            }
        }
    }
}

extern "C" void kernel_launch(void* const* d_in, const int* in_sizes, int n_in,
                              void* d_out, int out_size, void* d_ws, size_t ws_size,
                              hipStream_t stream)
{
    (void)in_sizes; (void)n_in; (void)out_size; (void)ws_size;
    const float* inputs = (const float*)d_in[0];
    const float* Wih_e  = (const float*)d_in[1];
    const float* Whh_e  = (const float*)d_in[2];
    const float* bih_e  = (const float*)d_in[3];
    const float* bhh_e  = (const float*)d_in[4];
    const float* Wih_d  = (const float*)d_in[5];
    const float* Whh_d  = (const float*)d_in[6];
    const float* bih_d  = (const float*)d_in[7];
    const float* bhh_d  = (const float*)d_in[8];
    const float* Wy     = (const float*)d_in[9];
    const float* by     = (const float*)d_in[10];
    float* out = (float*)d_out;

    hipLaunchKernelGGL(prep_kernel, dim3(256), dim3(256), 0, stream,
                       Wih_e, Whh_e, bih_e, bhh_e, Wih_d, Whh_d, bih_d, bhh_d, d_ws);
    hipLaunchKernelGGL(seq2seq_kernel, dim3(NBLOCKS), dim3(NTHREADS), 0, stream,
                       inputs, d_ws, Wy, by, out);
}